// Round 1
// baseline (120.904 us; speedup 1.0000x reference)
//
#include <hip/hip_runtime.h>

#define BATCH 16
#define SEQ   1024
#define DM    512
#define NST   32

// ---------------- pass 1: local chunk scans (g = dA*g + x), write chunk-end states
__global__ __launch_bounds__(256) void ssm_pass1(
    const float* __restrict__ x,
    const float* __restrict__ Alog_hr, const float* __restrict__ ldt_hr,
    const float* __restrict__ Alog_br, const float* __restrict__ ldt_br,
    float* __restrict__ ws_state, int nc, int cl)
{
    int idx = blockIdx.x * blockDim.x + threadIdx.x;   // ((ssm*16+b)*nc + c)*512 + d
    int d = idx & (DM - 1);
    int r = idx >> 9;
    int c = r % nc;  r /= nc;
    int b = r & 15;
    int ssm = r >> 4;

    const float* Alog = ssm ? Alog_br : Alog_hr;
    const float* ldt  = ssm ? ldt_br  : ldt_hr;

    float dt = expf(ldt[d]);
    float dA[NST];
#pragma unroll
    for (int n = 0; n < NST; ++n)
        dA[n] = expf(dt * expf(Alog[d * NST + n]));

    float g[NST];
#pragma unroll
    for (int n = 0; n < NST; ++n) g[n] = 0.f;

    const float* xp = x + ((size_t)b * SEQ + (size_t)c * cl) * DM + d;
#pragma unroll 4
    for (int t = 0; t < cl; ++t) {
        float xv = xp[(size_t)t * DM];
#pragma unroll
        for (int n = 0; n < NST; ++n) g[n] = fmaf(dA[n], g[n], xv);
    }

    size_t base = ((((size_t)ssm * BATCH + b) * nc + c) * NST) * DM + d;
#pragma unroll
    for (int n = 0; n < NST; ++n) ws_state[base + (size_t)n * DM] = g[n];
}

// ---------------- pass 2: scan across chunks; rewrite ws with corrected chunk-INITIAL states
__global__ __launch_bounds__(256) void ssm_pass2(
    const float* __restrict__ Alog_hr, const float* __restrict__ ldt_hr,
    const float* __restrict__ Alog_br, const float* __restrict__ ldt_br,
    float* __restrict__ ws_state, int nc, int cl)
{
    int idx = blockIdx.x * blockDim.x + threadIdx.x;   // (((ssm*16+b)*32+n)*512 + d)
    int d   = idx & (DM - 1);
    int n   = (idx >> 9) & (NST - 1);
    int b   = (idx >> 14) & 15;
    int ssm = idx >> 18;

    const float* Alog = ssm ? Alog_br : Alog_hr;
    const float* ldt  = ssm ? ldt_br  : ldt_hr;

    float dt = expf(ldt[d]);
    float A  = expf(Alog[d * NST + n]);
    float p  = expf((float)cl * dt * A);   // dA^cl

    size_t base    = ((((size_t)ssm * BATCH + b) * nc) * NST + n) * DM + d;
    size_t cstride = (size_t)NST * DM;

    float H = 0.f;
    for (int c = 0; c < nc; ++c) {
        float s = ws_state[base + (size_t)c * cstride];
        ws_state[base + (size_t)c * cstride] = H;   // init state for chunk c
        H = fmaf(p, H, s);                          // end state of chunk c
    }
}

// ---------------- pass 3: re-run chunk from corrected init, emit y (and combined for br)
template <int WRITE_COMB>
__global__ __launch_bounds__(256) void ssm_pass3(
    const float* __restrict__ x,
    const float* __restrict__ Alog, const float* __restrict__ Bm,
    const float* __restrict__ Cm,   const float* __restrict__ ldt,
    const float* __restrict__ w,
    const float* __restrict__ ws_state,
    const float* __restrict__ other_out,
    float* __restrict__ out, float* __restrict__ comb,
    int nc, int cl, int ssm)
{
    int idx = blockIdx.x * blockDim.x + threadIdx.x;   // (b*nc + c)*512 + d
    int d = idx & (DM - 1);
    int r = idx >> 9;
    int c = r % nc;
    int b = r / nc;

    float dt = expf(ldt[d]);
    float wd = w[d];

    float dA[NST], Cw[NST], g[NST];
#pragma unroll
    for (int n = 0; n < NST; ++n) {
        float a = expf(Alog[d * NST + n]);
        dA[n] = expf(dt * a);
        Cw[n] = Cm[d * NST + n] * Bm[d * NST + n] * dt * wd;
    }

    if (c == 0) {
#pragma unroll
        for (int n = 0; n < NST; ++n) g[n] = 0.f;
    } else {
        size_t base = ((((size_t)ssm * BATCH + b) * nc + c) * NST) * DM + d;
#pragma unroll
        for (int n = 0; n < NST; ++n) g[n] = ws_state[base + (size_t)n * DM];
    }

    size_t off = ((size_t)b * SEQ + (size_t)c * cl) * DM + d;
    const float* xp = x + off;
    float*       op = out + off;
    const float* hp = WRITE_COMB ? (other_out + off) : nullptr;
    float*       cp = WRITE_COMB ? (comb + off)      : nullptr;

#pragma unroll 2
    for (int t = 0; t < cl; ++t) {
        float xv = xp[(size_t)t * DM];
        float y0 = 0.f, y1 = 0.f, y2 = 0.f, y3 = 0.f;
#pragma unroll
        for (int n = 0; n < NST; n += 4) {
            g[n]     = fmaf(dA[n],     g[n],     xv);
            g[n + 1] = fmaf(dA[n + 1], g[n + 1], xv);
            g[n + 2] = fmaf(dA[n + 2], g[n + 2], xv);
            g[n + 3] = fmaf(dA[n + 3], g[n + 3], xv);
            y0 = fmaf(Cw[n],     g[n],     y0);
            y1 = fmaf(Cw[n + 1], g[n + 1], y1);
            y2 = fmaf(Cw[n + 2], g[n + 2], y2);
            y3 = fmaf(Cw[n + 3], g[n + 3], y3);
        }
        float y = (y0 + y1) + (y2 + y3);
        op[(size_t)t * DM] = y;
        if (WRITE_COMB)
            cp[(size_t)t * DM] = y + hp[(size_t)t * DM];
    }
}

extern "C" void kernel_launch(void* const* d_in, const int* in_sizes, int n_in,
                              void* d_out, int out_size, void* d_ws, size_t ws_size,
                              hipStream_t stream)
{
    (void)in_sizes; (void)n_in; (void)out_size;

    const float* x       = (const float*)d_in[0];
    const float* Alog_hr = (const float*)d_in[1];
    const float* B_hr    = (const float*)d_in[2];
    const float* C_hr    = (const float*)d_in[3];
    const float* ldt_hr  = (const float*)d_in[4];
    const float* Alog_br = (const float*)d_in[5];
    const float* B_br    = (const float*)d_in[6];
    const float* C_br    = (const float*)d_in[7];
    const float* ldt_br  = (const float*)d_in[8];
    const float* w_hr    = (const float*)d_in[9];
    const float* w_br    = (const float*)d_in[10];

    float* out    = (float*)d_out;
    const size_t one = (size_t)BATCH * SEQ * DM;
    float* out_hr = out;
    float* out_br = out + one;
    float* out_cb = out + 2 * one;
    float* ws     = (float*)d_ws;

    // pick chunk count that fits the workspace
    int nc = 16;
    while (nc > 1 && ws_size < (size_t)2 * BATCH * nc * NST * DM * sizeof(float)) nc >>= 1;
    int cl = SEQ / nc;

    if (nc > 1) {
        int total1 = 2 * BATCH * nc * DM;
        ssm_pass1<<<total1 / 256, 256, 0, stream>>>(x, Alog_hr, ldt_hr, Alog_br, ldt_br,
                                                    ws, nc, cl);
        int total2 = 2 * BATCH * NST * DM;
        ssm_pass2<<<total2 / 256, 256, 0, stream>>>(Alog_hr, ldt_hr, Alog_br, ldt_br,
                                                    ws, nc, cl);
    }

    int total3 = BATCH * nc * DM;
    ssm_pass3<0><<<total3 / 256, 256, 0, stream>>>(x, Alog_hr, B_hr, C_hr, ldt_hr, w_hr,
                                                   ws, nullptr, out_hr, nullptr, nc, cl, 0);
    ssm_pass3<1><<<total3 / 256, 256, 0, stream>>>(x, Alog_br, B_br, C_br, ldt_br, w_br,
                                                   ws, out_hr, out_br, out_cb, nc, cl, 1);
}

// Round 2
// 119.799 us; speedup vs baseline: 1.0092x; 1.0092x over previous
//
#include <hip/hip_runtime.h>

#define BATCH 16
#define SEQ   1024
#define DM    512
#define NST   32

// ---------------- setup: precompute dA and Cw=C*B*dt*w tables, layout [ssm][n][d]
__global__ __launch_bounds__(256) void ssm_setup(
    const float* __restrict__ Alog_hr, const float* __restrict__ B_hr,
    const float* __restrict__ C_hr,    const float* __restrict__ ldt_hr,
    const float* __restrict__ Alog_br, const float* __restrict__ B_br,
    const float* __restrict__ C_br,    const float* __restrict__ ldt_br,
    const float* __restrict__ w_hr,    const float* __restrict__ w_br,
    float* __restrict__ dA_tbl, float* __restrict__ Cw_tbl)
{
    int idx = blockIdx.x * blockDim.x + threadIdx.x;   // (ssm*NST + n)*DM + d
    int d   = idx & (DM - 1);
    int n   = (idx >> 9) & (NST - 1);
    int ssm = idx >> 14;

    const float* Alog = ssm ? Alog_br : Alog_hr;
    const float* Bm   = ssm ? B_br    : B_hr;
    const float* Cm   = ssm ? C_br    : C_hr;
    const float* ldt  = ssm ? ldt_br  : ldt_hr;
    const float* w    = ssm ? w_br    : w_hr;

    float dt = expf(ldt[d]);
    float a  = expf(Alog[d * NST + n]);
    dA_tbl[idx] = expf(dt * a);
    Cw_tbl[idx] = Cm[d * NST + n] * Bm[d * NST + n] * dt * w[d];
}

// ---------------- pass 1: local chunk scans for BOTH ssm (g = dA*g + x), write chunk-end states
__global__ __launch_bounds__(256) void ssm_pass1(
    const float* __restrict__ x,
    const float* __restrict__ dA_tbl,
    float* __restrict__ ws_state, int nc, int cl)
{
    int idx = blockIdx.x * blockDim.x + threadIdx.x;   // (b*nc + c)*DM + d
    int d = idx & (DM - 1);
    int r = idx >> 9;
    int c = r % nc;
    int b = r / nc;

    float dAh[NST], dAb[NST];
#pragma unroll
    for (int n = 0; n < NST; ++n) {
        dAh[n] = dA_tbl[(size_t)n * DM + d];
        dAb[n] = dA_tbl[((size_t)NST + n) * DM + d];
    }

    float gh[NST], gb[NST];
#pragma unroll
    for (int n = 0; n < NST; ++n) { gh[n] = 0.f; gb[n] = 0.f; }

    const float* xp = x + ((size_t)b * SEQ + (size_t)c * cl) * DM + d;
#pragma unroll 2
    for (int t = 0; t < cl; ++t) {
        float xv = xp[(size_t)t * DM];
#pragma unroll
        for (int n = 0; n < NST; ++n) {
            gh[n] = fmaf(dAh[n], gh[n], xv);
            gb[n] = fmaf(dAb[n], gb[n], xv);
        }
    }

    size_t baseh = (((size_t)b * nc + c) * NST) * DM + d;
    size_t baseb = ((((size_t)BATCH + b) * nc + c) * NST) * DM + d;
#pragma unroll
    for (int n = 0; n < NST; ++n) {
        ws_state[baseh + (size_t)n * DM] = gh[n];
        ws_state[baseb + (size_t)n * DM] = gb[n];
    }
}

// ---------------- pass 2: scan across chunks; rewrite ws with corrected chunk-INITIAL states
__global__ __launch_bounds__(256) void ssm_pass2(
    const float* __restrict__ Alog_hr, const float* __restrict__ ldt_hr,
    const float* __restrict__ Alog_br, const float* __restrict__ ldt_br,
    float* __restrict__ ws_state, int nc, int cl)
{
    int idx = blockIdx.x * blockDim.x + threadIdx.x;   // (((ssm*16+b)*NST+n)*DM + d)
    int d   = idx & (DM - 1);
    int n   = (idx >> 9) & (NST - 1);
    int b   = (idx >> 14) & 15;
    int ssm = idx >> 18;

    const float* Alog = ssm ? Alog_br : Alog_hr;
    const float* ldt  = ssm ? ldt_br  : ldt_hr;

    float dt = expf(ldt[d]);
    float A  = expf(Alog[d * NST + n]);
    float p  = expf((float)cl * dt * A);   // dA^cl

    size_t base    = ((((size_t)ssm * BATCH + b) * nc) * NST + n) * DM + d;
    size_t cstride = (size_t)NST * DM;

    float H = 0.f;
    for (int c = 0; c < nc; ++c) {
        float s = ws_state[base + (size_t)c * cstride];
        ws_state[base + (size_t)c * cstride] = H;   // init state for chunk c
        H = fmaf(p, H, s);                          // end state of chunk c
    }
}

// ---------------- pass 3: re-run chunk for BOTH ssm from corrected inits, emit hr, br, combined
__global__ __launch_bounds__(256) void ssm_pass3(
    const float* __restrict__ x,
    const float* __restrict__ dA_tbl, const float* __restrict__ Cw_tbl,
    const float* __restrict__ ws_state,
    float* __restrict__ out_hr, float* __restrict__ out_br, float* __restrict__ out_cb,
    int nc, int cl)
{
    int idx = blockIdx.x * blockDim.x + threadIdx.x;   // (b*nc + c)*DM + d
    int d = idx & (DM - 1);
    int r = idx >> 9;
    int c = r % nc;
    int b = r / nc;

    float dAh[NST], dAb[NST], Cwh[NST], Cwb[NST];
#pragma unroll
    for (int n = 0; n < NST; ++n) {
        dAh[n] = dA_tbl[(size_t)n * DM + d];
        dAb[n] = dA_tbl[((size_t)NST + n) * DM + d];
        Cwh[n] = Cw_tbl[(size_t)n * DM + d];
        Cwb[n] = Cw_tbl[((size_t)NST + n) * DM + d];
    }

    float gh[NST], gb[NST];
    if (c == 0) {
#pragma unroll
        for (int n = 0; n < NST; ++n) { gh[n] = 0.f; gb[n] = 0.f; }
    } else {
        size_t baseh = (((size_t)b * nc + c) * NST) * DM + d;
        size_t baseb = ((((size_t)BATCH + b) * nc + c) * NST) * DM + d;
#pragma unroll
        for (int n = 0; n < NST; ++n) {
            gh[n] = ws_state[baseh + (size_t)n * DM];
            gb[n] = ws_state[baseb + (size_t)n * DM];
        }
    }

    size_t off = ((size_t)b * SEQ + (size_t)c * cl) * DM + d;
    const float* xp = x + off;
    float* oh = out_hr + off;
    float* ob = out_br + off;
    float* oc = out_cb + off;

#pragma unroll 2
    for (int t = 0; t < cl; ++t) {
        float xv = xp[(size_t)t * DM];
        float yh0 = 0.f, yh1 = 0.f, yh2 = 0.f, yh3 = 0.f;
        float yb0 = 0.f, yb1 = 0.f, yb2 = 0.f, yb3 = 0.f;
#pragma unroll
        for (int n = 0; n < NST; n += 4) {
            gh[n]     = fmaf(dAh[n],     gh[n],     xv);
            gh[n + 1] = fmaf(dAh[n + 1], gh[n + 1], xv);
            gh[n + 2] = fmaf(dAh[n + 2], gh[n + 2], xv);
            gh[n + 3] = fmaf(dAh[n + 3], gh[n + 3], xv);
            yh0 = fmaf(Cwh[n],     gh[n],     yh0);
            yh1 = fmaf(Cwh[n + 1], gh[n + 1], yh1);
            yh2 = fmaf(Cwh[n + 2], gh[n + 2], yh2);
            yh3 = fmaf(Cwh[n + 3], gh[n + 3], yh3);
            gb[n]     = fmaf(dAb[n],     gb[n],     xv);
            gb[n + 1] = fmaf(dAb[n + 1], gb[n + 1], xv);
            gb[n + 2] = fmaf(dAb[n + 2], gb[n + 2], xv);
            gb[n + 3] = fmaf(dAb[n + 3], gb[n + 3], xv);
            yb0 = fmaf(Cwb[n],     gb[n],     yb0);
            yb1 = fmaf(Cwb[n + 1], gb[n + 1], yb1);
            yb2 = fmaf(Cwb[n + 2], gb[n + 2], yb2);
            yb3 = fmaf(Cwb[n + 3], gb[n + 3], yb3);
        }
        float yh = (yh0 + yh1) + (yh2 + yh3);
        float yb = (yb0 + yb1) + (yb2 + yb3);
        oh[(size_t)t * DM] = yh;
        ob[(size_t)t * DM] = yb;
        oc[(size_t)t * DM] = yh + yb;
    }
}

extern "C" void kernel_launch(void* const* d_in, const int* in_sizes, int n_in,
                              void* d_out, int out_size, void* d_ws, size_t ws_size,
                              hipStream_t stream)
{
    (void)in_sizes; (void)n_in; (void)out_size;

    const float* x       = (const float*)d_in[0];
    const float* Alog_hr = (const float*)d_in[1];
    const float* B_hr    = (const float*)d_in[2];
    const float* C_hr    = (const float*)d_in[3];
    const float* ldt_hr  = (const float*)d_in[4];
    const float* Alog_br = (const float*)d_in[5];
    const float* B_br    = (const float*)d_in[6];
    const float* C_br    = (const float*)d_in[7];
    const float* ldt_br  = (const float*)d_in[8];
    const float* w_hr    = (const float*)d_in[9];
    const float* w_br    = (const float*)d_in[10];

    float* out    = (float*)d_out;
    const size_t one = (size_t)BATCH * SEQ * DM;
    float* out_hr = out;
    float* out_br = out + one;
    float* out_cb = out + 2 * one;

    // ws layout: [dA_tbl 2*NST*DM][Cw_tbl 2*NST*DM][chunk states 2*BATCH*nc*NST*DM]
    float* dA_tbl = (float*)d_ws;
    float* Cw_tbl = dA_tbl + (size_t)2 * NST * DM;
    float* ws_st  = Cw_tbl + (size_t)2 * NST * DM;

    const size_t tbl_bytes = (size_t)4 * NST * DM * sizeof(float);
    int nc = 32;
    while (nc > 1 &&
           ws_size < tbl_bytes + (size_t)2 * BATCH * nc * NST * DM * sizeof(float))
        nc >>= 1;
    int cl = SEQ / nc;

    int total0 = 2 * NST * DM;
    ssm_setup<<<total0 / 256, 256, 0, stream>>>(Alog_hr, B_hr, C_hr, ldt_hr,
                                                Alog_br, B_br, C_br, ldt_br,
                                                w_hr, w_br, dA_tbl, Cw_tbl);

    if (nc > 1) {
        int total1 = BATCH * nc * DM;
        ssm_pass1<<<total1 / 256, 256, 0, stream>>>(x, dA_tbl, ws_st, nc, cl);
        int total2 = 2 * BATCH * NST * DM;
        ssm_pass2<<<total2 / 256, 256, 0, stream>>>(Alog_hr, ldt_hr, Alog_br, ldt_br,
                                                    ws_st, nc, cl);
    }

    int total3 = BATCH * nc * DM;
    ssm_pass3<<<total3 / 256, 256, 0, stream>>>(x, dA_tbl, Cw_tbl, ws_st,
                                                out_hr, out_br, out_cb, nc, cl);
}

// Round 3
// 119.218 us; speedup vs baseline: 1.0141x; 1.0049x over previous
//
#include <hip/hip_runtime.h>

#define BATCH 16
#define SEQ   1024
#define DM    512
#define NST   32

// ---------------- setup: precompute dA and Cw=C*B*dt*w tables, layout [ssm][n][d]
__global__ __launch_bounds__(256) void ssm_setup(
    const float* __restrict__ Alog_hr, const float* __restrict__ B_hr,
    const float* __restrict__ C_hr,    const float* __restrict__ ldt_hr,
    const float* __restrict__ Alog_br, const float* __restrict__ B_br,
    const float* __restrict__ C_br,    const float* __restrict__ ldt_br,
    const float* __restrict__ w_hr,    const float* __restrict__ w_br,
    float* __restrict__ dA_tbl, float* __restrict__ Cw_tbl)
{
    int idx = blockIdx.x * blockDim.x + threadIdx.x;   // (ssm*NST + n)*DM + d
    int d   = idx & (DM - 1);
    int n   = (idx >> 9) & (NST - 1);
    int ssm = idx >> 14;

    const float* Alog = ssm ? Alog_br : Alog_hr;
    const float* Bm   = ssm ? B_br    : B_hr;
    const float* Cm   = ssm ? C_br    : C_hr;
    const float* ldt  = ssm ? ldt_br  : ldt_hr;
    const float* w    = ssm ? w_br    : w_hr;

    float dt = expf(ldt[d]);
    float a  = expf(Alog[d * NST + n]);
    dA_tbl[idx] = expf(dt * a);
    Cw_tbl[idx] = Cm[d * NST + n] * Bm[d * NST + n] * dt * w[d];
}

// ---------------- pass 1: local chunk scans for BOTH ssm (g = dA*g + x), write chunk-end states
// launch_bounds(256,2): 2 waves/EU -> 256-VGPR budget so all 128 state/coeff floats stay in regs
__global__ __launch_bounds__(256, 2) void ssm_pass1(
    const float* __restrict__ x,
    const float* __restrict__ dA_tbl,
    float* __restrict__ ws_state, int nc, int cl)
{
    int idx = blockIdx.x * blockDim.x + threadIdx.x;   // (b*nc + c)*DM + d
    int d = idx & (DM - 1);
    int r = idx >> 9;
    int c = r % nc;
    int b = r / nc;

    float dAh[NST], dAb[NST];
#pragma unroll
    for (int n = 0; n < NST; ++n) {
        dAh[n] = dA_tbl[(size_t)n * DM + d];
        dAb[n] = dA_tbl[((size_t)NST + n) * DM + d];
    }

    float gh[NST], gb[NST];
#pragma unroll
    for (int n = 0; n < NST; ++n) { gh[n] = 0.f; gb[n] = 0.f; }

    const float* xp = x + ((size_t)b * SEQ + (size_t)c * cl) * DM + d;
#pragma unroll 2
    for (int t = 0; t < cl; ++t) {
        float xv = *xp;  xp += DM;
#pragma unroll
        for (int n = 0; n < NST; ++n) {
            gh[n] = fmaf(dAh[n], gh[n], xv);
            gb[n] = fmaf(dAb[n], gb[n], xv);
        }
    }

    float* sph = ws_state + (((size_t)b * nc + c) * NST) * DM + d;
    float* spb = ws_state + ((((size_t)BATCH + b) * nc + c) * NST) * DM + d;
#pragma unroll
    for (int n = 0; n < NST; ++n) {
        sph[(size_t)n * DM] = gh[n];
        spb[(size_t)n * DM] = gb[n];
    }
}

// ---------------- pass 2: scan across chunks; rewrite ws with corrected chunk-INITIAL states
__global__ __launch_bounds__(256) void ssm_pass2(
    const float* __restrict__ Alog_hr, const float* __restrict__ ldt_hr,
    const float* __restrict__ Alog_br, const float* __restrict__ ldt_br,
    float* __restrict__ ws_state, int nc, int cl)
{
    int idx = blockIdx.x * blockDim.x + threadIdx.x;   // (((ssm*16+b)*NST+n)*DM + d)
    int d   = idx & (DM - 1);
    int n   = (idx >> 9) & (NST - 1);
    int b   = (idx >> 14) & 15;
    int ssm = idx >> 18;

    const float* Alog = ssm ? Alog_br : Alog_hr;
    const float* ldt  = ssm ? ldt_br  : ldt_hr;

    float dt = expf(ldt[d]);
    float A  = expf(Alog[d * NST + n]);
    float p  = expf((float)cl * dt * A);   // dA^cl

    float* sp = ws_state + ((((size_t)ssm * BATCH + b) * nc) * NST + n) * DM + d;
    size_t cstride = (size_t)NST * DM;

    float H = 0.f;
    for (int c = 0; c < nc; ++c) {
        float s = *sp;
        *sp = H;                 // init state for chunk c
        H = fmaf(p, H, s);       // end state of chunk c
        sp += cstride;
    }
}

// ---------------- pass 3: re-run chunk for BOTH ssm from corrected inits, emit hr, br, combined
// launch_bounds(256,2): 256-VGPR budget for the 192 state/coeff floats
__global__ __launch_bounds__(256, 2) void ssm_pass3(
    const float* __restrict__ x,
    const float* __restrict__ dA_tbl, const float* __restrict__ Cw_tbl,
    const float* __restrict__ ws_state,
    float* __restrict__ out_hr, float* __restrict__ out_br, float* __restrict__ out_cb,
    int nc, int cl)
{
    int idx = blockIdx.x * blockDim.x + threadIdx.x;   // (b*nc + c)*DM + d
    int d = idx & (DM - 1);
    int r = idx >> 9;
    int c = r % nc;
    int b = r / nc;

    float dAh[NST], dAb[NST], Cwh[NST], Cwb[NST];
#pragma unroll
    for (int n = 0; n < NST; ++n) {
        dAh[n] = dA_tbl[(size_t)n * DM + d];
        dAb[n] = dA_tbl[((size_t)NST + n) * DM + d];
        Cwh[n] = Cw_tbl[(size_t)n * DM + d];
        Cwb[n] = Cw_tbl[((size_t)NST + n) * DM + d];
    }

    float gh[NST], gb[NST];
    if (c == 0) {
#pragma unroll
        for (int n = 0; n < NST; ++n) { gh[n] = 0.f; gb[n] = 0.f; }
    } else {
        const float* sph = ws_state + (((size_t)b * nc + c) * NST) * DM + d;
        const float* spb = ws_state + ((((size_t)BATCH + b) * nc + c) * NST) * DM + d;
#pragma unroll
        for (int n = 0; n < NST; ++n) {
            gh[n] = sph[(size_t)n * DM];
            gb[n] = spb[(size_t)n * DM];
        }
    }

    size_t off = ((size_t)b * SEQ + (size_t)c * cl) * DM + d;
    const float* xp = x + off;
    float* oh = out_hr + off;
    float* ob = out_br + off;
    float* oc = out_cb + off;

#pragma unroll 2
    for (int t = 0; t < cl; ++t) {
        float xv = *xp;  xp += DM;
        float yh0 = 0.f, yh1 = 0.f, yh2 = 0.f, yh3 = 0.f;
        float yb0 = 0.f, yb1 = 0.f, yb2 = 0.f, yb3 = 0.f;
#pragma unroll
        for (int n = 0; n < NST; n += 4) {
            gh[n]     = fmaf(dAh[n],     gh[n],     xv);
            gh[n + 1] = fmaf(dAh[n + 1], gh[n + 1], xv);
            gh[n + 2] = fmaf(dAh[n + 2], gh[n + 2], xv);
            gh[n + 3] = fmaf(dAh[n + 3], gh[n + 3], xv);
            yh0 = fmaf(Cwh[n],     gh[n],     yh0);
            yh1 = fmaf(Cwh[n + 1], gh[n + 1], yh1);
            yh2 = fmaf(Cwh[n + 2], gh[n + 2], yh2);
            yh3 = fmaf(Cwh[n + 3], gh[n + 3], yh3);
            gb[n]     = fmaf(dAb[n],     gb[n],     xv);
            gb[n + 1] = fmaf(dAb[n + 1], gb[n + 1], xv);
            gb[n + 2] = fmaf(dAb[n + 2], gb[n + 2], xv);
            gb[n + 3] = fmaf(dAb[n + 3], gb[n + 3], xv);
            yb0 = fmaf(Cwb[n],     gb[n],     yb0);
            yb1 = fmaf(Cwb[n + 1], gb[n + 1], yb1);
            yb2 = fmaf(Cwb[n + 2], gb[n + 2], yb2);
            yb3 = fmaf(Cwb[n + 3], gb[n + 3], yb3);
        }
        float yh = (yh0 + yh1) + (yh2 + yh3);
        float yb = (yb0 + yb1) + (yb2 + yb3);
        oh[0] = yh;  oh += DM;
        ob[0] = yb;  ob += DM;
        oc[0] = yh + yb;  oc += DM;
    }
}

extern "C" void kernel_launch(void* const* d_in, const int* in_sizes, int n_in,
                              void* d_out, int out_size, void* d_ws, size_t ws_size,
                              hipStream_t stream)
{
    (void)in_sizes; (void)n_in; (void)out_size;

    const float* x       = (const float*)d_in[0];
    const float* Alog_hr = (const float*)d_in[1];
    const float* B_hr    = (const float*)d_in[2];
    const float* C_hr    = (const float*)d_in[3];
    const float* ldt_hr  = (const float*)d_in[4];
    const float* Alog_br = (const float*)d_in[5];
    const float* B_br    = (const float*)d_in[6];
    const float* C_br    = (const float*)d_in[7];
    const float* ldt_br  = (const float*)d_in[8];
    const float* w_hr    = (const float*)d_in[9];
    const float* w_br    = (const float*)d_in[10];

    float* out    = (float*)d_out;
    const size_t one = (size_t)BATCH * SEQ * DM;
    float* out_hr = out;
    float* out_br = out + one;
    float* out_cb = out + 2 * one;

    // ws layout: [dA_tbl 2*NST*DM][Cw_tbl 2*NST*DM][chunk states 2*BATCH*nc*NST*DM]
    float* dA_tbl = (float*)d_ws;
    float* Cw_tbl = dA_tbl + (size_t)2 * NST * DM;
    float* ws_st  = Cw_tbl + (size_t)2 * NST * DM;

    const size_t tbl_bytes = (size_t)4 * NST * DM * sizeof(float);
    int nc = 32;
    while (nc > 1 &&
           ws_size < tbl_bytes + (size_t)2 * BATCH * nc * NST * DM * sizeof(float))
        nc >>= 1;
    int cl = SEQ / nc;

    int total0 = 2 * NST * DM;
    ssm_setup<<<total0 / 256, 256, 0, stream>>>(Alog_hr, B_hr, C_hr, ldt_hr,
                                                Alog_br, B_br, C_br, ldt_br,
                                                w_hr, w_br, dA_tbl, Cw_tbl);

    if (nc > 1) {
        int total1 = BATCH * nc * DM;
        ssm_pass1<<<total1 / 256, 256, 0, stream>>>(x, dA_tbl, ws_st, nc, cl);
        int total2 = 2 * BATCH * NST * DM;
        ssm_pass2<<<total2 / 256, 256, 0, stream>>>(Alog_hr, ldt_hr, Alog_br, ldt_br,
                                                    ws_st, nc, cl);
    }

    int total3 = BATCH * nc * DM;
    ssm_pass3<<<total3 / 256, 256, 0, stream>>>(x, dA_tbl, Cw_tbl, ws_st,
                                                out_hr, out_br, out_cb, nc, cl);
}

// Round 4
// 93.772 us; speedup vs baseline: 1.2893x; 1.2714x over previous
//
#include <hip/hip_runtime.h>

#define BATCH 16
#define SEQ   1024
#define DM    512
#define NST   32
#define NPT   8          // states per thread per ssm in pass3 (NST/4)

// ---------------- setup: precompute dA and Cw=C*B*dt*w tables, layout [ssm][n][d]
__global__ __launch_bounds__(256) void ssm_setup(
    const float* __restrict__ Alog_hr, const float* __restrict__ B_hr,
    const float* __restrict__ C_hr,    const float* __restrict__ ldt_hr,
    const float* __restrict__ Alog_br, const float* __restrict__ B_br,
    const float* __restrict__ C_br,    const float* __restrict__ ldt_br,
    const float* __restrict__ w_hr,    const float* __restrict__ w_br,
    float* __restrict__ dA_tbl, float* __restrict__ Cw_tbl)
{
    int idx = blockIdx.x * blockDim.x + threadIdx.x;   // (ssm*NST + n)*DM + d
    int d   = idx & (DM - 1);
    int n   = (idx >> 9) & (NST - 1);
    int ssm = idx >> 14;

    const float* Alog = ssm ? Alog_br : Alog_hr;
    const float* Bm   = ssm ? B_br    : B_hr;
    const float* Cm   = ssm ? C_br    : C_hr;
    const float* ldt  = ssm ? ldt_br  : ldt_hr;
    const float* w    = ssm ? w_br    : w_hr;

    float dt = expf(ldt[d]);
    float a  = expf(Alog[d * NST + n]);
    dA_tbl[idx] = expf(dt * a);
    Cw_tbl[idx] = Cm[d * NST + n] * Bm[d * NST + n] * dt * w[d];
}

// ---------------- pass 1: local chunk scans, ONE ssm per thread (64 live floats)
__global__ __launch_bounds__(256) void ssm_pass1(
    const float* __restrict__ x,
    const float* __restrict__ dA_tbl,
    float* __restrict__ ws_state, int nc, int cl)
{
    int tid  = threadIdx.x;
    int bid  = blockIdx.x;          // ((ssm*BATCH+b)*nc + c)*2 + dblk
    int dblk = bid & 1;
    int r    = bid >> 1;
    int c    = r % nc;  r /= nc;
    int b    = r & (BATCH - 1);
    int ssm  = r >> 4;
    int d    = (dblk << 8) + tid;

    const float* tb = dA_tbl + (size_t)ssm * NST * DM + d;
    float dA[NST];
#pragma unroll
    for (int n = 0; n < NST; ++n) dA[n] = tb[(size_t)n * DM];

    float g[NST];
#pragma unroll
    for (int n = 0; n < NST; ++n) g[n] = 0.f;

    const float* xp = x + ((size_t)b * SEQ + (size_t)c * cl) * DM + d;
#pragma unroll 2
    for (int t = 0; t < cl; ++t) {
        float xv = *xp;  xp += DM;
#pragma unroll
        for (int n = 0; n < NST; ++n) g[n] = fmaf(dA[n], g[n], xv);
    }

    float* sp = ws_state + ((((size_t)ssm * BATCH + b) * nc + c) * NST) * DM + d;
#pragma unroll
    for (int n = 0; n < NST; ++n) sp[(size_t)n * DM] = g[n];
}

// ---------------- pass 2: scan across chunks; rewrite ws with corrected chunk-INITIAL states
__global__ __launch_bounds__(256) void ssm_pass2(
    const float* __restrict__ Alog_hr, const float* __restrict__ ldt_hr,
    const float* __restrict__ Alog_br, const float* __restrict__ ldt_br,
    float* __restrict__ ws_state, int nc, int cl)
{
    int idx = blockIdx.x * blockDim.x + threadIdx.x;   // (((ssm*16+b)*NST+n)*DM + d)
    int d   = idx & (DM - 1);
    int n   = (idx >> 9) & (NST - 1);
    int b   = (idx >> 14) & 15;
    int ssm = idx >> 18;

    const float* Alog = ssm ? Alog_br : Alog_hr;
    const float* ldt  = ssm ? ldt_br  : ldt_hr;

    float dt = expf(ldt[d]);
    float A  = expf(Alog[d * NST + n]);
    float p  = expf((float)cl * dt * A);   // dA^cl

    float* sp = ws_state + ((((size_t)ssm * BATCH + b) * nc) * NST + n) * DM + d;
    size_t cstride = (size_t)NST * DM;

    float H = 0.f;
    for (int c = 0; c < nc; ++c) {
        float s = *sp;
        *sp = H;                 // init state for chunk c
        H = fmaf(p, H, s);       // end state of chunk c
        sp += cstride;
    }
}

// ---------------- pass 3: n-split x4 across lane groups; both ssm; shfl-reduce the dot
// lane = tid&63; nq = lane>>4 owns states [nq*8, nq*8+8); dlo = lane&15.
// Live set: 6*NPT = 48 floats -> no remat/spill.
__global__ __launch_bounds__(256) void ssm_pass3(
    const float* __restrict__ x,
    const float* __restrict__ dA_tbl, const float* __restrict__ Cw_tbl,
    const float* __restrict__ ws_state,
    float* __restrict__ out_hr, float* __restrict__ out_br, float* __restrict__ out_cb,
    int nc, int cl)
{
    int tid  = threadIdx.x;
    int lane = tid & 63;
    int wave = tid >> 6;
    int nq   = lane >> 4;
    int dlo  = lane & 15;
    int bid  = blockIdx.x;          // (b*nc + c)*8 + dblk
    int dblk = bid & 7;
    int r    = bid >> 3;
    int c    = r % nc;
    int b    = r / nc;
    int d    = (dblk << 6) + (wave << 4) + dlo;
    int n0   = nq * NPT;

    float dAh[NPT], dAb[NPT], Cwh[NPT], Cwb[NPT];
#pragma unroll
    for (int i = 0; i < NPT; ++i) {
        size_t ih = (size_t)(n0 + i) * DM + d;
        size_t ib = (size_t)(NST + n0 + i) * DM + d;
        dAh[i] = dA_tbl[ih];
        dAb[i] = dA_tbl[ib];
        Cwh[i] = Cw_tbl[ih];
        Cwb[i] = Cw_tbl[ib];
    }

    float gh[NPT], gb[NPT];
    if (c == 0) {
#pragma unroll
        for (int i = 0; i < NPT; ++i) { gh[i] = 0.f; gb[i] = 0.f; }
    } else {
        const float* sph = ws_state + (((size_t)b * nc + c) * NST + n0) * DM + d;
        const float* spb = sph + (size_t)BATCH * nc * NST * DM;
#pragma unroll
        for (int i = 0; i < NPT; ++i) {
            gh[i] = sph[(size_t)i * DM];
            gb[i] = spb[(size_t)i * DM];
        }
    }

    size_t off = ((size_t)b * SEQ + (size_t)c * cl) * DM + d;
    const float* xp = x + off;
    float* op = (nq == 0 ? out_hr : (nq == 1 ? out_br : out_cb)) + off;

#pragma unroll 2
    for (int t = 0; t < cl; ++t) {
        float xv = *xp;  xp += DM;

        float yh0 = 0.f, yh1 = 0.f, yb0 = 0.f, yb1 = 0.f;
#pragma unroll
        for (int i = 0; i < NPT; i += 2) {
            gh[i]     = fmaf(dAh[i],     gh[i],     xv);
            gh[i + 1] = fmaf(dAh[i + 1], gh[i + 1], xv);
            gb[i]     = fmaf(dAb[i],     gb[i],     xv);
            gb[i + 1] = fmaf(dAb[i + 1], gb[i + 1], xv);
            yh0 = fmaf(Cwh[i],     gh[i],     yh0);
            yh1 = fmaf(Cwh[i + 1], gh[i + 1], yh1);
            yb0 = fmaf(Cwb[i],     gb[i],     yb0);
            yb1 = fmaf(Cwb[i + 1], gb[i + 1], yb1);
        }
        float yh = yh0 + yh1;
        float yb = yb0 + yb1;

        // reduce over nq (lane bits 4,5); interleave hr/br for ILP
        float th = __shfl_xor(yh, 16, 64);
        float tb_ = __shfl_xor(yb, 16, 64);
        yh += th;  yb += tb_;
        th  = __shfl_xor(yh, 32, 64);
        tb_ = __shfl_xor(yb, 32, 64);
        yh += th;  yb += tb_;

        float val = (nq == 0) ? yh : ((nq == 1) ? yb : yh + yb);
        *op = val;  op += DM;
    }
}

extern "C" void kernel_launch(void* const* d_in, const int* in_sizes, int n_in,
                              void* d_out, int out_size, void* d_ws, size_t ws_size,
                              hipStream_t stream)
{
    (void)in_sizes; (void)n_in; (void)out_size;

    const float* x       = (const float*)d_in[0];
    const float* Alog_hr = (const float*)d_in[1];
    const float* B_hr    = (const float*)d_in[2];
    const float* C_hr    = (const float*)d_in[3];
    const float* ldt_hr  = (const float*)d_in[4];
    const float* Alog_br = (const float*)d_in[5];
    const float* B_br    = (const float*)d_in[6];
    const float* C_br    = (const float*)d_in[7];
    const float* ldt_br  = (const float*)d_in[8];
    const float* w_hr    = (const float*)d_in[9];
    const float* w_br    = (const float*)d_in[10];

    float* out    = (float*)d_out;
    const size_t one = (size_t)BATCH * SEQ * DM;
    float* out_hr = out;
    float* out_br = out + one;
    float* out_cb = out + 2 * one;

    // ws layout: [dA_tbl 2*NST*DM][Cw_tbl 2*NST*DM][chunk states 2*BATCH*nc*NST*DM]
    float* dA_tbl = (float*)d_ws;
    float* Cw_tbl = dA_tbl + (size_t)2 * NST * DM;
    float* ws_st  = Cw_tbl + (size_t)2 * NST * DM;

    const size_t tbl_bytes = (size_t)4 * NST * DM * sizeof(float);
    int nc = 16;
    while (nc > 1 &&
           ws_size < tbl_bytes + (size_t)2 * BATCH * nc * NST * DM * sizeof(float))
        nc >>= 1;
    int cl = SEQ / nc;

    int total0 = 2 * NST * DM;
    ssm_setup<<<total0 / 256, 256, 0, stream>>>(Alog_hr, B_hr, C_hr, ldt_hr,
                                                Alog_br, B_br, C_br, ldt_br,
                                                w_hr, w_br, dA_tbl, Cw_tbl);

    if (nc > 1) {
        int nblk1 = 2 * BATCH * nc * 2;          // (ssm,b,c) x 2 d-blocks of 256
        ssm_pass1<<<nblk1, 256, 0, stream>>>(x, dA_tbl, ws_st, nc, cl);
        int total2 = 2 * BATCH * NST * DM;
        ssm_pass2<<<total2 / 256, 256, 0, stream>>>(Alog_hr, ldt_hr, Alog_br, ldt_br,
                                                    ws_st, nc, cl);
    }

    int nblk3 = BATCH * nc * 8;                  // (b,c) x 8 d-blocks of 64 (x4 nq)
    ssm_pass3<<<nblk3, 256, 0, stream>>>(x, dA_tbl, Cw_tbl, ws_st,
                                         out_hr, out_br, out_cb, nc, cl);
}